// Round 1
// baseline (10184.116 us; speedup 1.0000x reference)
//
#include <hip/hip_runtime.h>
#include <math.h>

// LSTM: I=5, H=64, L=3, O=1, B=1024, T=256, fp32.
// Fused single-kernel design:
//   grid = 512 blocks x 256 threads; each block owns TB=2 batch elements.
//   Time processed in chunks of TC=64; per chunk: layer0 -> layer1 -> layer2,
//   inter-layer h-sequences staged in LDS (h0c/h1c). Recurrent h state in LDS,
//   c state in VGPRs of the combine threads. No global intermediates.
//   Thread g owns gate row g: w_ih[g][:], w_hh[g][:] held in VGPRs (reloaded
//   per layer phase from L2). h broadcast via uniform-address ds_read_b128:
//   1 LDS instr -> 8 FMAs (4 k x TB=2) -> VALU-bound.

constexpr int Hh = 64;
constexpr int G4 = 256;   // 4*H gate rows
constexpr int Tt = 256;   // timesteps
constexpr int In = 5;     // input size
constexpr int TB = 2;     // batch elems per block
constexpr int TC = 64;    // timestep chunk
constexpr int NB = 512;   // blocks (NB*TB = 1024 = B)

__device__ __forceinline__ float sigm(float x) {
    return 1.0f / (1.0f + __expf(-x));
}
__device__ __forceinline__ float tanh_fast(float x) {
    float ax = fabsf(x);
    float t = __expf(-2.0f * ax);      // in (0,1], no overflow
    float r = (1.0f - t) / (1.0f + t);
    return copysignf(r, x);
}

__global__ __launch_bounds__(256, 2) void lstm3_fused(
    const float* __restrict__ x,
    const float* __restrict__ w_ih0, const float* __restrict__ w_hh0,
    const float* __restrict__ b_ih0, const float* __restrict__ b_hh0,
    const float* __restrict__ w_ih1, const float* __restrict__ w_hh1,
    const float* __restrict__ b_ih1, const float* __restrict__ b_hh1,
    const float* __restrict__ w_ih2, const float* __restrict__ w_hh2,
    const float* __restrict__ b_ih2, const float* __restrict__ b_hh2,
    const float* __restrict__ w_fc,  const float* __restrict__ b_fc,
    float* __restrict__ out)
{
    __shared__ alignas(16) float h0c[TB][TC][Hh];   // layer0 output chunk (32 KB)
    __shared__ alignas(16) float h1c[TB][TC][Hh];   // layer1 output chunk (32 KB)
    __shared__ alignas(16) float hst[3][TB][Hh];    // recurrent h state per layer
    __shared__ alignas(16) float gbuf[TB][G4];      // activated gates
    __shared__ alignas(16) float xs[TB][TC][In];    // staged input chunk

    const int tid = threadIdx.x;
    const int g   = tid;          // gate row 0..255
    const int gt  = g >> 6;       // 0:i 1:f 2:g~ 3:o  (wave-uniform)
    const int b0  = blockIdx.x * TB;
    const int cu  = tid & (Hh - 1);   // combine: hidden unit
    const int cb  = tid >> 6;         // combine: batch elem (valid if < TB)

    float creg0 = 0.f, creg1 = 0.f, creg2 = 0.f;   // c state (threads tid < TB*Hh)

    for (int i = tid; i < 3 * TB * Hh; i += 256) ((float*)hst)[i] = 0.f;

    float wih[Hh];   // input weights for this gate row (l=0 uses first 5)
    float whh[Hh];   // recurrent weights
    float bias;

    for (int chunk = 0; chunk < Tt / TC; ++chunk) {
        const int t0 = chunk * TC;

        // ---- stage x chunk (coalesced-ish, tiny: 640 floats) ----
        for (int i = tid; i < TB * TC * In; i += 256) {
            int b  = i / (TC * In);
            int r  = i - b * (TC * In);
            int t  = r / In;
            int cc = r - t * In;
            xs[b][t][cc] = x[((size_t)(b0 + b) * Tt + (t0 + t)) * In + cc];
        }

        // ================= layer 0 =================
        {
            #pragma unroll
            for (int i = 0; i < In; ++i) wih[i] = w_ih0[g * In + i];
            const float4* w4 = reinterpret_cast<const float4*>(w_hh0 + g * Hh);
            #pragma unroll
            for (int q = 0; q < Hh / 4; ++q) {
                float4 v = w4[q];
                whh[4*q+0] = v.x; whh[4*q+1] = v.y; whh[4*q+2] = v.z; whh[4*q+3] = v.w;
            }
            bias = b_ih0[g] + b_hh0[g];
        }
        __syncthreads();   // xs staged + (chunk 0) hst zero-init visible

        for (int tt = 0; tt < TC; ++tt) {
            float acc[TB];
            #pragma unroll
            for (int b = 0; b < TB; ++b) {
                float a_in = bias;
                #pragma unroll
                for (int i = 0; i < In; ++i) a_in += wih[i] * xs[b][tt][i];
                float a_r0 = 0.f, a_r1 = 0.f;
                #pragma unroll
                for (int q = 0; q < Hh / 8; ++q) {
                    float4 hA = *reinterpret_cast<const float4*>(&hst[0][b][8*q]);
                    float4 hB = *reinterpret_cast<const float4*>(&hst[0][b][8*q+4]);
                    a_r0 += whh[8*q+0]*hA.x + whh[8*q+1]*hA.y + whh[8*q+2]*hA.z + whh[8*q+3]*hA.w;
                    a_r1 += whh[8*q+4]*hB.x + whh[8*q+5]*hB.y + whh[8*q+6]*hB.z + whh[8*q+7]*hB.w;
                }
                acc[b] = a_in + a_r0 + a_r1;
            }
            #pragma unroll
            for (int b = 0; b < TB; ++b) {
                float v = acc[b];
                float av;
                if (gt == 2) av = tanh_fast(v); else av = sigm(v);  // wave-uniform branch
                gbuf[b][g] = av;
            }
            __syncthreads();
            if (tid < TB * Hh) {
                float iv = gbuf[cb][cu];
                float fv = gbuf[cb][Hh + cu];
                float gv = gbuf[cb][2*Hh + cu];
                float ov = gbuf[cb][3*Hh + cu];
                float c_ = fv * creg0 + iv * gv;
                creg0 = c_;
                float hn = ov * tanh_fast(c_);
                hst[0][cb][cu] = hn;
                h0c[cb][tt][cu] = hn;
            }
            __syncthreads();
        }

        // ================= layer 1 =================
        {
            const float4* wi4 = reinterpret_cast<const float4*>(w_ih1 + g * Hh);
            const float4* wh4 = reinterpret_cast<const float4*>(w_hh1 + g * Hh);
            #pragma unroll
            for (int q = 0; q < Hh / 4; ++q) {
                float4 vi = wi4[q];
                wih[4*q+0] = vi.x; wih[4*q+1] = vi.y; wih[4*q+2] = vi.z; wih[4*q+3] = vi.w;
                float4 vh = wh4[q];
                whh[4*q+0] = vh.x; whh[4*q+1] = vh.y; whh[4*q+2] = vh.z; whh[4*q+3] = vh.w;
            }
            bias = b_ih1[g] + b_hh1[g];
        }
        // h0c fully written (last combine barrier of layer-0 loop)

        for (int tt = 0; tt < TC; ++tt) {
            float acc[TB];
            #pragma unroll
            for (int b = 0; b < TB; ++b) {
                float a_i0 = bias, a_i1 = 0.f, a_r0 = 0.f, a_r1 = 0.f;
                #pragma unroll
                for (int q = 0; q < Hh / 8; ++q) {
                    float4 iA = *reinterpret_cast<const float4*>(&h0c[b][tt][8*q]);
                    float4 iB = *reinterpret_cast<const float4*>(&h0c[b][tt][8*q+4]);
                    a_i0 += wih[8*q+0]*iA.x + wih[8*q+1]*iA.y + wih[8*q+2]*iA.z + wih[8*q+3]*iA.w;
                    a_i1 += wih[8*q+4]*iB.x + wih[8*q+5]*iB.y + wih[8*q+6]*iB.z + wih[8*q+7]*iB.w;
                    float4 hA = *reinterpret_cast<const float4*>(&hst[1][b][8*q]);
                    float4 hB = *reinterpret_cast<const float4*>(&hst[1][b][8*q+4]);
                    a_r0 += whh[8*q+0]*hA.x + whh[8*q+1]*hA.y + whh[8*q+2]*hA.z + whh[8*q+3]*hA.w;
                    a_r1 += whh[8*q+4]*hB.x + whh[8*q+5]*hB.y + whh[8*q+6]*hB.z + whh[8*q+7]*hB.w;
                }
                acc[b] = (a_i0 + a_i1) + (a_r0 + a_r1);
            }
            #pragma unroll
            for (int b = 0; b < TB; ++b) {
                float v = acc[b];
                float av;
                if (gt == 2) av = tanh_fast(v); else av = sigm(v);
                gbuf[b][g] = av;
            }
            __syncthreads();
            if (tid < TB * Hh) {
                float iv = gbuf[cb][cu];
                float fv = gbuf[cb][Hh + cu];
                float gv = gbuf[cb][2*Hh + cu];
                float ov = gbuf[cb][3*Hh + cu];
                float c_ = fv * creg1 + iv * gv;
                creg1 = c_;
                float hn = ov * tanh_fast(c_);
                hst[1][cb][cu] = hn;
                h1c[cb][tt][cu] = hn;
            }
            __syncthreads();
        }

        // ================= layer 2 =================
        {
            const float4* wi4 = reinterpret_cast<const float4*>(w_ih2 + g * Hh);
            const float4* wh4 = reinterpret_cast<const float4*>(w_hh2 + g * Hh);
            #pragma unroll
            for (int q = 0; q < Hh / 4; ++q) {
                float4 vi = wi4[q];
                wih[4*q+0] = vi.x; wih[4*q+1] = vi.y; wih[4*q+2] = vi.z; wih[4*q+3] = vi.w;
                float4 vh = wh4[q];
                whh[4*q+0] = vh.x; whh[4*q+1] = vh.y; whh[4*q+2] = vh.z; whh[4*q+3] = vh.w;
            }
            bias = b_ih2[g] + b_hh2[g];
        }

        for (int tt = 0; tt < TC; ++tt) {
            float acc[TB];
            #pragma unroll
            for (int b = 0; b < TB; ++b) {
                float a_i0 = bias, a_i1 = 0.f, a_r0 = 0.f, a_r1 = 0.f;
                #pragma unroll
                for (int q = 0; q < Hh / 8; ++q) {
                    float4 iA = *reinterpret_cast<const float4*>(&h1c[b][tt][8*q]);
                    float4 iB = *reinterpret_cast<const float4*>(&h1c[b][tt][8*q+4]);
                    a_i0 += wih[8*q+0]*iA.x + wih[8*q+1]*iA.y + wih[8*q+2]*iA.z + wih[8*q+3]*iA.w;
                    a_i1 += wih[8*q+4]*iB.x + wih[8*q+5]*iB.y + wih[8*q+6]*iB.z + wih[8*q+7]*iB.w;
                    float4 hA = *reinterpret_cast<const float4*>(&hst[2][b][8*q]);
                    float4 hB = *reinterpret_cast<const float4*>(&hst[2][b][8*q+4]);
                    a_r0 += whh[8*q+0]*hA.x + whh[8*q+1]*hA.y + whh[8*q+2]*hA.z + whh[8*q+3]*hA.w;
                    a_r1 += whh[8*q+4]*hB.x + whh[8*q+5]*hB.y + whh[8*q+6]*hB.z + whh[8*q+7]*hB.w;
                }
                acc[b] = (a_i0 + a_i1) + (a_r0 + a_r1);
            }
            #pragma unroll
            for (int b = 0; b < TB; ++b) {
                float v = acc[b];
                float av;
                if (gt == 2) av = tanh_fast(v); else av = sigm(v);
                gbuf[b][g] = av;
            }
            __syncthreads();
            if (tid < TB * Hh) {
                float iv = gbuf[cb][cu];
                float fv = gbuf[cb][Hh + cu];
                float gv = gbuf[cb][2*Hh + cu];
                float ov = gbuf[cb][3*Hh + cu];
                float c_ = fv * creg2 + iv * gv;
                creg2 = c_;
                float hn = ov * tanh_fast(c_);
                hst[2][cb][cu] = hn;   // layer-2 h sequence not needed, only state
            }
            __syncthreads();
        }
    }

    // ---- final FC on h2 at t = T-1 ----
    if (tid < TB * Hh) {
        float p = hst[2][cb][cu] * w_fc[cu];
        #pragma unroll
        for (int off = 32; off > 0; off >>= 1) p += __shfl_down(p, off, 64);
        if (cu == 0) out[b0 + cb] = p + b_fc[0];
    }
}

extern "C" void kernel_launch(void* const* d_in, const int* in_sizes, int n_in,
                              void* d_out, int out_size, void* d_ws, size_t ws_size,
                              hipStream_t stream) {
    const float* x     = (const float*)d_in[0];
    const float* w_ih0 = (const float*)d_in[1];
    const float* w_hh0 = (const float*)d_in[2];
    const float* b_ih0 = (const float*)d_in[3];
    const float* b_hh0 = (const float*)d_in[4];
    const float* w_ih1 = (const float*)d_in[5];
    const float* w_hh1 = (const float*)d_in[6];
    const float* b_ih1 = (const float*)d_in[7];
    const float* b_hh1 = (const float*)d_in[8];
    const float* w_ih2 = (const float*)d_in[9];
    const float* w_hh2 = (const float*)d_in[10];
    const float* b_ih2 = (const float*)d_in[11];
    const float* b_hh2 = (const float*)d_in[12];
    const float* w_fc  = (const float*)d_in[13];
    const float* b_fc  = (const float*)d_in[14];
    float* out = (float*)d_out;

    lstm3_fused<<<NB, 256, 0, stream>>>(x,
        w_ih0, w_hh0, b_ih0, b_hh0,
        w_ih1, w_hh1, b_ih1, b_hh1,
        w_ih2, w_hh2, b_ih2, b_hh2,
        w_fc, b_fc, out);
}

// Round 2
// 7842.189 us; speedup vs baseline: 1.2986x; 1.2986x over previous
//
#include <hip/hip_runtime.h>
#include <math.h>

// LSTM: I=5, H=64, L=3, O=1, B=1024, T=256, fp32.
// Round-2 fix: round-1 spilled (128 weight floats/thread -> scratch, 23.8 GB
// HBM traffic). Now k-split S=2 across lane pairs: tid = 2*g + s, thread
// holds wih[32]+whh[32] (64 VGPRs); pair-combined with one __shfl_xor.
// 512 threads/block, TB=2 batch/block, 512 blocks, 2 blocks/CU.
// Inter-layer h sequences staged in LDS chunks; c state in combine-thread
// VGPRs; zero global intermediates.

constexpr int Hh = 64;
constexpr int G4 = 256;   // 4*H gate rows
constexpr int Tt = 256;   // timesteps
constexpr int In = 5;     // input size
constexpr int TB = 2;     // batch elems per block
constexpr int TC = 64;    // timestep chunk
constexpr int NB = 512;   // blocks (NB*TB = 1024 = B)
constexpr int NT = 512;   // threads per block

__device__ __forceinline__ float sigm(float x) {
    return 1.0f / (1.0f + __expf(-x));
}
__device__ __forceinline__ float tanh_fast(float x) {
    float ax = fabsf(x);
    float t = __expf(-2.0f * ax);      // in (0,1], no overflow
    float r = (1.0f - t) / (1.0f + t);
    return copysignf(r, x);
}

__global__ __launch_bounds__(NT, 4) void lstm3_fused(
    const float* __restrict__ x,
    const float* __restrict__ w_ih0, const float* __restrict__ w_hh0,
    const float* __restrict__ b_ih0, const float* __restrict__ b_hh0,
    const float* __restrict__ w_ih1, const float* __restrict__ w_hh1,
    const float* __restrict__ b_ih1, const float* __restrict__ b_hh1,
    const float* __restrict__ w_ih2, const float* __restrict__ w_hh2,
    const float* __restrict__ b_ih2, const float* __restrict__ b_hh2,
    const float* __restrict__ w_fc,  const float* __restrict__ b_fc,
    float* __restrict__ out)
{
    __shared__ alignas(16) float h0c[TB][TC][Hh];   // layer0 output chunk (32 KB)
    __shared__ alignas(16) float h1c[TB][TC][Hh];   // layer1 output chunk (32 KB)
    __shared__ alignas(16) float hst[3][TB][Hh];    // recurrent h state per layer
    __shared__ alignas(16) float gbuf[TB][G4];      // activated gates
    __shared__ alignas(16) float xs[TB][TC][In];    // staged input chunk

    const int tid = threadIdx.x;
    const int g   = tid >> 1;         // gate row 0..255
    const int s   = tid & 1;          // k-half 0..1
    const int gt  = g >> 6;           // 0:i 1:f 2:g~ 3:o  (wave-uniform: g spans 32-aligned ranges)
    const int b0  = blockIdx.x * TB;
    const int cu  = tid & (Hh - 1);   // combine: hidden unit (tid < 128)
    const int cb  = tid >> 6;         // combine: batch elem

    float creg0 = 0.f, creg1 = 0.f, creg2 = 0.f;   // c state (threads tid < TB*Hh)

    for (int i = tid; i < 3 * TB * Hh; i += NT) ((float*)hst)[i] = 0.f;

    float wi[32];   // input-weight half-row for this (g, s)
    float wh[32];   // recurrent-weight half-row
    float bias;

    for (int chunk = 0; chunk < Tt / TC; ++chunk) {
        const int t0 = chunk * TC;

        // ---- stage x chunk (tiny: 640 floats) ----
        for (int i = tid; i < TB * TC * In; i += NT) {
            int b  = i / (TC * In);
            int r  = i - b * (TC * In);
            int t  = r / In;
            int cc = r - t * In;
            xs[b][t][cc] = x[((size_t)(b0 + b) * Tt + (t0 + t)) * In + cc];
        }

        // ================= layer 0 =================
        {
            #pragma unroll
            for (int i = 0; i < In; ++i) wi[i] = (s == 0) ? w_ih0[g * In + i] : 0.f;
            const float4* w4 = reinterpret_cast<const float4*>(w_hh0 + g * Hh + 32 * s);
            #pragma unroll
            for (int q = 0; q < 8; ++q) {
                float4 v = w4[q];
                wh[4*q+0] = v.x; wh[4*q+1] = v.y; wh[4*q+2] = v.z; wh[4*q+3] = v.w;
            }
            bias = b_ih0[g] + b_hh0[g];
        }
        __syncthreads();   // xs staged + (chunk 0) hst zero-init visible

        for (int tt = 0; tt < TC; ++tt) {
            float acc[TB];
            #pragma unroll
            for (int b = 0; b < TB; ++b) {
                float a_in = (s == 0) ? bias : 0.f;
                #pragma unroll
                for (int i = 0; i < In; ++i) a_in += wi[i] * xs[b][tt][i];
                float r0 = 0.f, r1 = 0.f;
                const float4* hp = reinterpret_cast<const float4*>(&hst[0][b][32 * s]);
                #pragma unroll
                for (int q = 0; q < 4; ++q) {
                    float4 hA = hp[2*q], hB = hp[2*q+1];
                    r0 += wh[8*q+0]*hA.x + wh[8*q+1]*hA.y + wh[8*q+2]*hA.z + wh[8*q+3]*hA.w;
                    r1 += wh[8*q+4]*hB.x + wh[8*q+5]*hB.y + wh[8*q+6]*hB.z + wh[8*q+7]*hB.w;
                }
                acc[b] = a_in + r0 + r1;
            }
            #pragma unroll
            for (int b = 0; b < TB; ++b) {
                float v = acc[b] + __shfl_xor(acc[b], 1, 64);  // pair-combine halves
                float av = (gt == 2) ? tanh_fast(v) : sigm(v); // wave-uniform branch
                if (s == 0) gbuf[b][g] = av;
            }
            __syncthreads();
            if (tid < TB * Hh) {
                float iv = gbuf[cb][cu];
                float fv = gbuf[cb][Hh + cu];
                float gv = gbuf[cb][2*Hh + cu];
                float ov = gbuf[cb][3*Hh + cu];
                float c_ = fv * creg0 + iv * gv;
                creg0 = c_;
                float hn = ov * tanh_fast(c_);
                hst[0][cb][cu] = hn;
                h0c[cb][tt][cu] = hn;
            }
            __syncthreads();
        }

        // ================= layer 1 =================
        {
            const float4* wi4 = reinterpret_cast<const float4*>(w_ih1 + g * Hh + 32 * s);
            const float4* wh4 = reinterpret_cast<const float4*>(w_hh1 + g * Hh + 32 * s);
            #pragma unroll
            for (int q = 0; q < 8; ++q) {
                float4 vi = wi4[q];
                wi[4*q+0] = vi.x; wi[4*q+1] = vi.y; wi[4*q+2] = vi.z; wi[4*q+3] = vi.w;
                float4 vh = wh4[q];
                wh[4*q+0] = vh.x; wh[4*q+1] = vh.y; wh[4*q+2] = vh.z; wh[4*q+3] = vh.w;
            }
            bias = b_ih1[g] + b_hh1[g];
        }
        // h0c fully written (last combine barrier of layer-0 loop)

        for (int tt = 0; tt < TC; ++tt) {
            float acc[TB];
            #pragma unroll
            for (int b = 0; b < TB; ++b) {
                float a0 = (s == 0) ? bias : 0.f, a1 = 0.f, r0 = 0.f, r1 = 0.f;
                const float4* ip = reinterpret_cast<const float4*>(&h0c[b][tt][32 * s]);
                const float4* hp = reinterpret_cast<const float4*>(&hst[1][b][32 * s]);
                #pragma unroll
                for (int q = 0; q < 4; ++q) {
                    float4 iA = ip[2*q], iB = ip[2*q+1];
                    a0 += wi[8*q+0]*iA.x + wi[8*q+1]*iA.y + wi[8*q+2]*iA.z + wi[8*q+3]*iA.w;
                    a1 += wi[8*q+4]*iB.x + wi[8*q+5]*iB.y + wi[8*q+6]*iB.z + wi[8*q+7]*iB.w;
                    float4 hA = hp[2*q], hB = hp[2*q+1];
                    r0 += wh[8*q+0]*hA.x + wh[8*q+1]*hA.y + wh[8*q+2]*hA.z + wh[8*q+3]*hA.w;
                    r1 += wh[8*q+4]*hB.x + wh[8*q+5]*hB.y + wh[8*q+6]*hB.z + wh[8*q+7]*hB.w;
                }
                acc[b] = (a0 + a1) + (r0 + r1);
            }
            #pragma unroll
            for (int b = 0; b < TB; ++b) {
                float v = acc[b] + __shfl_xor(acc[b], 1, 64);
                float av = (gt == 2) ? tanh_fast(v) : sigm(v);
                if (s == 0) gbuf[b][g] = av;
            }
            __syncthreads();
            if (tid < TB * Hh) {
                float iv = gbuf[cb][cu];
                float fv = gbuf[cb][Hh + cu];
                float gv = gbuf[cb][2*Hh + cu];
                float ov = gbuf[cb][3*Hh + cu];
                float c_ = fv * creg1 + iv * gv;
                creg1 = c_;
                float hn = ov * tanh_fast(c_);
                hst[1][cb][cu] = hn;
                h1c[cb][tt][cu] = hn;
            }
            __syncthreads();
        }

        // ================= layer 2 =================
        {
            const float4* wi4 = reinterpret_cast<const float4*>(w_ih2 + g * Hh + 32 * s);
            const float4* wh4 = reinterpret_cast<const float4*>(w_hh2 + g * Hh + 32 * s);
            #pragma unroll
            for (int q = 0; q < 8; ++q) {
                float4 vi = wi4[q];
                wi[4*q+0] = vi.x; wi[4*q+1] = vi.y; wi[4*q+2] = vi.z; wi[4*q+3] = vi.w;
                float4 vh = wh4[q];
                wh[4*q+0] = vh.x; wh[4*q+1] = vh.y; wh[4*q+2] = vh.z; wh[4*q+3] = vh.w;
            }
            bias = b_ih2[g] + b_hh2[g];
        }

        for (int tt = 0; tt < TC; ++tt) {
            float acc[TB];
            #pragma unroll
            for (int b = 0; b < TB; ++b) {
                float a0 = (s == 0) ? bias : 0.f, a1 = 0.f, r0 = 0.f, r1 = 0.f;
                const float4* ip = reinterpret_cast<const float4*>(&h1c[b][tt][32 * s]);
                const float4* hp = reinterpret_cast<const float4*>(&hst[2][b][32 * s]);
                #pragma unroll
                for (int q = 0; q < 4; ++q) {
                    float4 iA = ip[2*q], iB = ip[2*q+1];
                    a0 += wi[8*q+0]*iA.x + wi[8*q+1]*iA.y + wi[8*q+2]*iA.z + wi[8*q+3]*iA.w;
                    a1 += wi[8*q+4]*iB.x + wi[8*q+5]*iB.y + wi[8*q+6]*iB.z + wi[8*q+7]*iB.w;
                    float4 hA = hp[2*q], hB = hp[2*q+1];
                    r0 += wh[8*q+0]*hA.x + wh[8*q+1]*hA.y + wh[8*q+2]*hA.z + wh[8*q+3]*hA.w;
                    r1 += wh[8*q+4]*hB.x + wh[8*q+5]*hB.y + wh[8*q+6]*hB.z + wh[8*q+7]*hB.w;
                }
                acc[b] = (a0 + a1) + (r0 + r1);
            }
            #pragma unroll
            for (int b = 0; b < TB; ++b) {
                float v = acc[b] + __shfl_xor(acc[b], 1, 64);
                float av = (gt == 2) ? tanh_fast(v) : sigm(v);
                if (s == 0) gbuf[b][g] = av;
            }
            __syncthreads();
            if (tid < TB * Hh) {
                float iv = gbuf[cb][cu];
                float fv = gbuf[cb][Hh + cu];
                float gv = gbuf[cb][2*Hh + cu];
                float ov = gbuf[cb][3*Hh + cu];
                float c_ = fv * creg2 + iv * gv;
                creg2 = c_;
                float hn = ov * tanh_fast(c_);
                hst[2][cb][cu] = hn;   // only state needed for layer 2
            }
            __syncthreads();
        }
    }

    // ---- final FC on h2 at t = T-1 ----
    if (tid < TB * Hh) {
        float p = hst[2][cb][cu] * w_fc[cu];
        #pragma unroll
        for (int off = 32; off > 0; off >>= 1) p += __shfl_down(p, off, 64);
        if (cu == 0) out[b0 + cb] = p + b_fc[0];
    }
}

extern "C" void kernel_launch(void* const* d_in, const int* in_sizes, int n_in,
                              void* d_out, int out_size, void* d_ws, size_t ws_size,
                              hipStream_t stream) {
    const float* x     = (const float*)d_in[0];
    const float* w_ih0 = (const float*)d_in[1];
    const float* w_hh0 = (const float*)d_in[2];
    const float* b_ih0 = (const float*)d_in[3];
    const float* b_hh0 = (const float*)d_in[4];
    const float* w_ih1 = (const float*)d_in[5];
    const float* w_hh1 = (const float*)d_in[6];
    const float* b_ih1 = (const float*)d_in[7];
    const float* b_hh1 = (const float*)d_in[8];
    const float* w_ih2 = (const float*)d_in[9];
    const float* w_hh2 = (const float*)d_in[10];
    const float* b_ih2 = (const float*)d_in[11];
    const float* b_hh2 = (const float*)d_in[12];
    const float* w_fc  = (const float*)d_in[13];
    const float* b_fc  = (const float*)d_in[14];
    float* out = (float*)d_out;

    lstm3_fused<<<NB, NT, 0, stream>>>(x,
        w_ih0, w_hh0, b_ih0, b_hh0,
        w_ih1, w_hh1, b_ih1, b_hh1,
        w_ih2, w_hh2, b_ih2, b_hh2,
        w_fc, b_fc, out);
}

// Round 4
// 1518.203 us; speedup vs baseline: 6.7080x; 5.1654x over previous
//
#include <hip/hip_runtime.h>
#include <math.h>

// LSTM: I=5, H=64, L=3, O=1, B=1024, T=256, fp32.
// Round-4: r3 structure + bugfix. r3 failed because layers 1/2 initialized
// batch-elem-1's accumulator to 0 instead of bias (layer 0 had it right).
// Structure: 512 blocks x 512 thr, TB=2 batch/block, k-split s=tid&1 (32
// weights/half), gate row g=tid>>1. Weights in NAMED float4 registers,
// __launch_bounds__(512,2) -> 4 waves/EU -> 128 VGPR cap, runtime chunk
// bound + asm memory barrier to prevent weight-load hoisting (anti-spill,
// see r1/r2: indexed arrays + low VGPR cap caused 21+ GB scratch traffic).

constexpr int Hh = 64;
constexpr int G4 = 256;   // 4*H gate rows
constexpr int Tt = 256;   // timesteps
constexpr int In = 5;     // input size
constexpr int TB = 2;     // batch elems per block
constexpr int TC = 64;    // timestep chunk
constexpr int NB = 512;   // blocks (NB*TB = 1024 = B)
constexpr int NT = 512;   // threads per block

__device__ __forceinline__ float sigm(float x) { return 1.0f / (1.0f + __expf(-x)); }
__device__ __forceinline__ float tanh_fast(float x) {
    float ax = fabsf(x);
    float t = __expf(-2.0f * ax);      // in (0,1], no overflow
    float r = (1.0f - t) / (1.0f + t);
    return copysignf(r, x);
}

#define DOT4(W, H) ((W).x*(H).x + (W).y*(H).y + (W).z*(H).z + (W).w*(H).w)

// macros reference wh0..wh7 / wi0..wi7 named float4s from enclosing scope
#define REC32(res, HPTR) do { \
    const float4* hp_ = reinterpret_cast<const float4*>(HPTR); \
    float4 hA=hp_[0], hB=hp_[1], hC=hp_[2], hD=hp_[3]; \
    float4 hE=hp_[4], hF=hp_[5], hG=hp_[6], hH=hp_[7]; \
    res += (DOT4(wh0,hA)+DOT4(wh1,hB)) + (DOT4(wh2,hC)+DOT4(wh3,hD)) \
         + (DOT4(wh4,hE)+DOT4(wh5,hF)) + (DOT4(wh6,hG)+DOT4(wh7,hH)); \
} while (0)

#define IN32(res, HPTR) do { \
    const float4* ip_ = reinterpret_cast<const float4*>(HPTR); \
    float4 iA=ip_[0], iB=ip_[1], iC=ip_[2], iD=ip_[3]; \
    float4 iE=ip_[4], iF=ip_[5], iG=ip_[6], iH=ip_[7]; \
    res += (DOT4(wi0,iA)+DOT4(wi1,iB)) + (DOT4(wi2,iC)+DOT4(wi3,iD)) \
         + (DOT4(wi4,iE)+DOT4(wi5,iF)) + (DOT4(wi6,iG)+DOT4(wi7,iH)); \
} while (0)

__global__ __launch_bounds__(NT, 2) void lstm3_fused(
    const float* __restrict__ x,
    const float* __restrict__ w_ih0, const float* __restrict__ w_hh0,
    const float* __restrict__ b_ih0, const float* __restrict__ b_hh0,
    const float* __restrict__ w_ih1, const float* __restrict__ w_hh1,
    const float* __restrict__ b_ih1, const float* __restrict__ b_hh1,
    const float* __restrict__ w_ih2, const float* __restrict__ w_hh2,
    const float* __restrict__ b_ih2, const float* __restrict__ b_hh2,
    const float* __restrict__ w_fc,  const float* __restrict__ b_fc,
    float* __restrict__ out, int nch)
{
    __shared__ alignas(16) float h0c[TB][TC][Hh];   // layer0 output chunk (32 KB)
    __shared__ alignas(16) float h1c[TB][TC][Hh];   // layer1 output chunk (32 KB)
    __shared__ alignas(16) float hst[3][TB][Hh];    // recurrent h state per layer
    __shared__ alignas(16) float gbuf[TB][G4];      // activated gates
    __shared__ alignas(16) float xs[TB][TC][In];    // staged input chunk

    const int tid = threadIdx.x;
    const int g   = tid >> 1;         // gate row 0..255
    const int s   = tid & 1;          // k-half 0..1
    const int gt  = tid >> 7;         // 0:i 1:f 2:g~ 3:o (wave-uniform)
    const int b0  = blockIdx.x * TB;
    const int cu  = tid & (Hh - 1);   // combine: hidden unit (tid < 128)
    const int cb  = tid >> 6;         // combine: batch elem

    float c0s = 0.f, c1s = 0.f, c2s = 0.f;   // c state (threads tid < TB*Hh)

    for (int i = tid; i < 3 * TB * Hh; i += NT) ((float*)hst)[i] = 0.f;

    #pragma unroll 1
    for (int chunk = 0; chunk < nch; ++chunk) {
        const int t0 = chunk * TC;

        // ---- stage x chunk (tiny: 640 floats) ----
        for (int i = tid; i < TB * TC * In; i += NT) {
            int b  = i / (TC * In);
            int r  = i - b * (TC * In);
            int t  = r / In;
            int cc = r - t * In;
            xs[b][t][cc] = x[((size_t)(b0 + b) * Tt + (t0 + t)) * In + cc];
        }

        // ================= layer 0 =================
        {
            asm volatile("" ::: "memory");   // block hoist of weight loads
            float wiA0=0.f, wiA1=0.f, wiA2=0.f, wiA3=0.f, wiA4=0.f, bias=0.f;
            if (s == 0) {
                wiA0 = w_ih0[g*In+0]; wiA1 = w_ih0[g*In+1]; wiA2 = w_ih0[g*In+2];
                wiA3 = w_ih0[g*In+3]; wiA4 = w_ih0[g*In+4];
                bias = b_ih0[g] + b_hh0[g];
            }
            const float4* w4 = reinterpret_cast<const float4*>(w_hh0 + g * Hh + 32 * s);
            float4 wh0=w4[0], wh1=w4[1], wh2=w4[2], wh3=w4[3];
            float4 wh4=w4[4], wh5=w4[5], wh6=w4[6], wh7=w4[7];
            __syncthreads();   // xs staged (+ chunk 0: hst zero-init visible)

            for (int tt = 0; tt < TC; ++tt) {
                float a0 = bias + wiA0*xs[0][tt][0] + wiA1*xs[0][tt][1]
                         + wiA2*xs[0][tt][2] + wiA3*xs[0][tt][3] + wiA4*xs[0][tt][4];
                REC32(a0, &hst[0][0][32*s]);
                float a1 = bias + wiA0*xs[1][tt][0] + wiA1*xs[1][tt][1]
                         + wiA2*xs[1][tt][2] + wiA3*xs[1][tt][3] + wiA4*xs[1][tt][4];
                REC32(a1, &hst[0][1][32*s]);
                float v0 = a0 + __shfl_xor(a0, 1, 64);
                float v1 = a1 + __shfl_xor(a1, 1, 64);
                float av0 = (gt == 2) ? tanh_fast(v0) : sigm(v0);
                float av1 = (gt == 2) ? tanh_fast(v1) : sigm(v1);
                if (s == 0) { gbuf[0][g] = av0; gbuf[1][g] = av1; }
                __syncthreads();
                if (tid < TB * Hh) {
                    float iv = gbuf[cb][cu];
                    float fv = gbuf[cb][Hh + cu];
                    float gv = gbuf[cb][2*Hh + cu];
                    float ov = gbuf[cb][3*Hh + cu];
                    float c_ = fv * c0s + iv * gv;
                    c0s = c_;
                    float hn = ov * tanh_fast(c_);
                    hst[0][cb][cu] = hn;
                    h0c[cb][tt][cu] = hn;
                }
                __syncthreads();
            }
        }

        // ================= layer 1 =================
        {
            asm volatile("" ::: "memory");
            const float4* wi4p = reinterpret_cast<const float4*>(w_ih1 + g * Hh + 32 * s);
            float4 wi0=wi4p[0], wi1=wi4p[1], wi2=wi4p[2], wi3=wi4p[3];
            float4 wi4=wi4p[4], wi5=wi4p[5], wi6=wi4p[6], wi7=wi4p[7];
            const float4* wh4p = reinterpret_cast<const float4*>(w_hh1 + g * Hh + 32 * s);
            float4 wh0=wh4p[0], wh1=wh4p[1], wh2=wh4p[2], wh3=wh4p[3];
            float4 wh4=wh4p[4], wh5=wh4p[5], wh6=wh4p[6], wh7=wh4p[7];
            float bias = (s == 0) ? (b_ih1[g] + b_hh1[g]) : 0.f;
            // h0c fully written (final barrier of layer-0 loop)

            for (int tt = 0; tt < TC; ++tt) {
                float a0 = bias;
                IN32(a0, &h0c[0][tt][32*s]);
                REC32(a0, &hst[1][0][32*s]);
                float a1 = bias;                      // r3 BUG WAS HERE (was 0.f)
                IN32(a1, &h0c[1][tt][32*s]);
                REC32(a1, &hst[1][1][32*s]);
                float v0 = a0 + __shfl_xor(a0, 1, 64);
                float v1 = a1 + __shfl_xor(a1, 1, 64);
                float av0 = (gt == 2) ? tanh_fast(v0) : sigm(v0);
                float av1 = (gt == 2) ? tanh_fast(v1) : sigm(v1);
                if (s == 0) { gbuf[0][g] = av0; gbuf[1][g] = av1; }
                __syncthreads();
                if (tid < TB * Hh) {
                    float iv = gbuf[cb][cu];
                    float fv = gbuf[cb][Hh + cu];
                    float gv = gbuf[cb][2*Hh + cu];
                    float ov = gbuf[cb][3*Hh + cu];
                    float c_ = fv * c1s + iv * gv;
                    c1s = c_;
                    float hn = ov * tanh_fast(c_);
                    hst[1][cb][cu] = hn;
                    h1c[cb][tt][cu] = hn;
                }
                __syncthreads();
            }
        }

        // ================= layer 2 =================
        {
            asm volatile("" ::: "memory");
            const float4* wi4p = reinterpret_cast<const float4*>(w_ih2 + g * Hh + 32 * s);
            float4 wi0=wi4p[0], wi1=wi4p[1], wi2=wi4p[2], wi3=wi4p[3];
            float4 wi4=wi4p[4], wi5=wi4p[5], wi6=wi4p[6], wi7=wi4p[7];
            const float4* wh4p = reinterpret_cast<const float4*>(w_hh2 + g * Hh + 32 * s);
            float4 wh0=wh4p[0], wh1=wh4p[1], wh2=wh4p[2], wh3=wh4p[3];
            float4 wh4=wh4p[4], wh5=wh4p[5], wh6=wh4p[6], wh7=wh4p[7];
            float bias = (s == 0) ? (b_ih2[g] + b_hh2[g]) : 0.f;

            for (int tt = 0; tt < TC; ++tt) {
                float a0 = bias;
                IN32(a0, &h1c[0][tt][32*s]);
                REC32(a0, &hst[2][0][32*s]);
                float a1 = bias;                      // r3 BUG WAS HERE (was 0.f)
                IN32(a1, &h1c[1][tt][32*s]);
                REC32(a1, &hst[2][1][32*s]);
                float v0 = a0 + __shfl_xor(a0, 1, 64);
                float v1 = a1 + __shfl_xor(a1, 1, 64);
                float av0 = (gt == 2) ? tanh_fast(v0) : sigm(v0);
                float av1 = (gt == 2) ? tanh_fast(v1) : sigm(v1);
                if (s == 0) { gbuf[0][g] = av0; gbuf[1][g] = av1; }
                __syncthreads();
                if (tid < TB * Hh) {
                    float iv = gbuf[cb][cu];
                    float fv = gbuf[cb][Hh + cu];
                    float gv = gbuf[cb][2*Hh + cu];
                    float ov = gbuf[cb][3*Hh + cu];
                    float c_ = fv * c2s + iv * gv;
                    c2s = c_;
                    float hn = ov * tanh_fast(c_);
                    hst[2][cb][cu] = hn;   // only state needed for layer 2
                }
                __syncthreads();
            }
        }
    }

    // ---- final FC on h2 at t = T-1 ----
    if (tid < TB * Hh) {
        float p = hst[2][cb][cu] * w_fc[cu];
        #pragma unroll
        for (int off = 32; off > 0; off >>= 1) p += __shfl_down(p, off, 64);
        if (cu == 0) out[b0 + cb] = p + b_fc[0];
    }
}

extern "C" void kernel_launch(void* const* d_in, const int* in_sizes, int n_in,
                              void* d_out, int out_size, void* d_ws, size_t ws_size,
                              hipStream_t stream) {
    const float* x     = (const float*)d_in[0];
    const float* w_ih0 = (const float*)d_in[1];
    const float* w_hh0 = (const float*)d_in[2];
    const float* b_ih0 = (const float*)d_in[3];
    const float* b_hh0 = (const float*)d_in[4];
    const float* w_ih1 = (const float*)d_in[5];
    const float* w_hh1 = (const float*)d_in[6];
    const float* b_ih1 = (const float*)d_in[7];
    const float* b_hh1 = (const float*)d_in[8];
    const float* w_ih2 = (const float*)d_in[9];
    const float* w_hh2 = (const float*)d_in[10];
    const float* b_ih2 = (const float*)d_in[11];
    const float* b_hh2 = (const float*)d_in[12];
    const float* w_fc  = (const float*)d_in[13];
    const float* b_fc  = (const float*)d_in[14];
    float* out = (float*)d_out;

    lstm3_fused<<<NB, NT, 0, stream>>>(x,
        w_ih0, w_hh0, b_ih0, b_hh0,
        w_ih1, w_hh1, b_ih1, b_hh1,
        w_ih2, w_hh2, b_ih2, b_hh2,
        w_fc, b_fc, out, Tt / TC);
}